// Round 10
// baseline (321.537 us; speedup 1.0000x reference)
//
#include <hip/hip_runtime.h>
#include <hip/hip_bf16.h>
#include <stdint.h>
#include <math.h>

#define N_NODES 8192
#define FDIM 128
#define LRELU_ALPHA 0.2f
#define BETA 0.3f
#define NEGV -9000000000000000.0f
#define THR 8.0f

typedef __attribute__((ext_vector_type(8))) short bf16x8;
typedef __attribute__((ext_vector_type(4))) float f32x4;

__device__ __forceinline__ uint16_t f2b(float x) {
  union { float f; uint32_t u; } v; v.f = x;
  uint32_t r = v.u + 0x7FFFu + ((v.u >> 16) & 1u);
  return (uint16_t)(r >> 16);
}

// ---------------------------------------------------------------------------
// prep_wh: Wh = h @ w.  Writes Wh fp32, Wh bf16 (row-major), Wh^T bf16.
// ---------------------------------------------------------------------------
__global__ void __launch_bounds__(256) prep_wh(
    const float* __restrict__ h, const float* __restrict__ w,
    float* __restrict__ whf, uint16_t* __restrict__ whb,
    uint16_t* __restrict__ whtb) {
  __shared__ float hs[32][128];
  const int t = threadIdx.x;
  const int rb = blockIdx.x * 32;
#pragma unroll
  for (int k = 0; k < 16; ++k) {
    int idx = t + k * 256;
    int r = idx >> 7, c = idx & 127;
    hs[r][c] = h[(size_t)(rb + r) * FDIM + c];
  }
  __syncthreads();
  const int c = t & 127;
  const int half = t >> 7;
  const int r0 = half * 16;
  float acc[16];
#pragma unroll
  for (int k = 0; k < 16; ++k) acc[k] = 0.f;
  for (int kk = 0; kk < 128; ++kk) {
    float wv = w[kk * FDIM + c];
#pragma unroll
    for (int k = 0; k < 16; ++k) acc[k] += hs[r0 + k][kk] * wv;
  }
  uint16_t tb[16];
#pragma unroll
  for (int k = 0; k < 16; ++k) {
    int r = rb + r0 + k;
    whf[(size_t)r * FDIM + c] = acc[k];
    uint16_t b = f2b(acc[k]);
    whb[(size_t)r * FDIM + c] = b;
    tb[k] = b;
  }
  uint16_t* dst = whtb + (size_t)c * N_NODES + rb + r0;
  bf16x8 v0, v1;
#pragma unroll
  for (int k = 0; k < 8; ++k) { v0[k] = (short)tb[k]; v1[k] = (short)tb[k + 8]; }
  *(bf16x8*)(dst) = v0;
  *(bf16x8*)(dst + 8) = v1;
}

// ---------------------------------------------------------------------------
// prep_s1: s1[i] = dot(Wh[i], a1[i]);  a2 -> bf16.
// ---------------------------------------------------------------------------
__global__ void __launch_bounds__(256) prep_s1(
    const float* __restrict__ whf, const float* __restrict__ a,
    float* __restrict__ s1, uint16_t* __restrict__ a2b) {
  const int t = threadIdx.x;
  const int rb = blockIdx.x * 32;
  const int wv = t >> 6;
  const int lane = t & 63;
  const int r = rb + wv * 8 + (lane >> 3);
  const int c0 = (lane & 7) * 16;
  float s = 0.f;
#pragma unroll
  for (int k = 0; k < 16; ++k) {
    s += whf[(size_t)r * FDIM + c0 + k] * a[(size_t)r * 256 + c0 + k];
  }
  s += __shfl_xor(s, 1);
  s += __shfl_xor(s, 2);
  s += __shfl_xor(s, 4);
  if ((lane & 7) == 0) s1[r] = s;
#pragma unroll
  for (int k = 0; k < 16; ++k) {
    int idx = t + k * 256;
    int rr = idx >> 7, cc = idx & 127;
    a2b[(size_t)(rb + rr) * FDIM + cc] = f2b(a[(size_t)(rb + rr) * 256 + 128 + cc]);
  }
}

// ---------------------------------------------------------------------------
// Macros for the pipelined main loop.  All array indices are compile-time
// literals (rule #20: no runtime-indexed ext_vector arrays).
// ---------------------------------------------------------------------------
#define GAT_LOADB(BW, JB)                                                     \
  do {                                                                        \
    _Pragma("unroll") for (int nt = 0; nt < 2; ++nt)                          \
      _Pragma("unroll") for (int ks = 0; ks < 4; ++ks)                        \
        BW[nt][ks] = *(const bf16x8*)(whb + (size_t)((JB) + nt * 16 + ln) * FDIM + ks * 32 + lg * 8); \
  } while (0)

#define GAT_BODY(BW, JB)                                                      \
  do {                                                                        \
    int adjv[2][2][4];                                                        \
    _Pragma("unroll") for (int it = 0; it < 2; ++it)                          \
      _Pragma("unroll") for (int nt = 0; nt < 2; ++nt)                        \
        _Pragma("unroll") for (int r = 0; r < 4; ++r)                         \
          adjv[it][nt][r] = adjbase[(size_t)(it * 16 + r) * N_NODES + (JB) + nt * 16]; \
    f32x4 sacc[2][2];                                                         \
    _Pragma("unroll") for (int it = 0; it < 2; ++it)                          \
      _Pragma("unroll") for (int nt = 0; nt < 2; ++nt)                        \
        sacc[it][nt] = (f32x4){0.f, 0.f, 0.f, 0.f};                           \
    _Pragma("unroll") for (int nt = 0; nt < 2; ++nt)                          \
      _Pragma("unroll") for (int ks = 0; ks < 4; ++ks) {                      \
        sacc[0][nt] = __builtin_amdgcn_mfma_f32_16x16x32_bf16(af[0][ks], BW[nt][ks], sacc[0][nt], 0, 0, 0); \
        sacc[1][nt] = __builtin_amdgcn_mfma_f32_16x16x32_bf16(af[1][ks], BW[nt][ks], sacc[1][nt], 0, 0, 0); \
      }                                                                       \
    float e[2][2][4];                                                         \
    _Pragma("unroll") for (int it = 0; it < 2; ++it)                          \
      _Pragma("unroll") for (int nt = 0; nt < 2; ++nt)                        \
        _Pragma("unroll") for (int r = 0; r < 4; ++r) {                       \
          float v = s1v[it][r] + sacc[it][nt][r];                             \
          v = (v > 0.f) ? v : LRELU_ALPHA * v;                                \
          e[it][nt][r] = (adjv[it][nt][r] > 0) ? v : NEGV;                    \
        }                                                                     \
    bool upd = false;                                                         \
    _Pragma("unroll") for (int it = 0; it < 2; ++it)                          \
      _Pragma("unroll") for (int r = 0; r < 4; ++r)                           \
        upd |= (e[it][0][r] > mrun[it][r] + THR) || (e[it][1][r] > mrun[it][r] + THR); \
    if (__any(upd)) {                                                         \
      _Pragma("unroll") for (int it = 0; it < 2; ++it) {                      \
        float mx[4];                                                          \
        _Pragma("unroll") for (int r = 0; r < 4; ++r) mx[r] = fmaxf(e[it][0][r], e[it][1][r]); \
        _Pragma("unroll") for (int off = 1; off <= 8; off <<= 1)              \
          _Pragma("unroll") for (int r = 0; r < 4; ++r) mx[r] = fmaxf(mx[r], __shfl_xor(mx[r], off)); \
        _Pragma("unroll") for (int r = 0; r < 4; ++r) {                       \
          float mn = fmaxf(mrun[it][r], mx[r]);                               \
          float al = __expf(mrun[it][r] - mn);                                \
          mrun[it][r] = mn;                                                   \
          lsum[it][r] *= al;                                                  \
          _Pragma("unroll") for (int ft = 0; ft < 8; ++ft) O[it][ft][r] *= al; \
        }                                                                     \
      }                                                                       \
    }                                                                         \
    _Pragma("unroll") for (int it = 0; it < 2; ++it)                          \
      _Pragma("unroll") for (int nt = 0; nt < 2; ++nt)                        \
        _Pragma("unroll") for (int r = 0; r < 4; ++r) {                       \
          float p = __expf(e[it][nt][r] - mrun[it][r]);                       \
          lsum[it][r] += p;                                                   \
          plds[wv][it * 16 + lg * 4 + r][nt * 16 + ln] = f2b(p);              \
        }                                                                     \
    bf16x8 pa0 = *(const bf16x8*)&plds[wv][ln][lg * 8];                       \
    bf16x8 pa1 = *(const bf16x8*)&plds[wv][16 + ln][lg * 8];                  \
    _Pragma("unroll") for (int ft = 0; ft < 8; ++ft) {                        \
      bf16x8 bv = *(const bf16x8*)(whtb + (size_t)(ft * 16 + ln) * N_NODES + (JB) + lg * 8); \
      O[0][ft] = __builtin_amdgcn_mfma_f32_16x16x32_bf16(pa0, bv, O[0][ft], 0, 0, 0); \
      O[1][ft] = __builtin_amdgcn_mfma_f32_16x16x32_bf16(pa1, bv, O[1][ft], 0, 0, 0); \
    }                                                                         \
  } while (0)

// ---------------------------------------------------------------------------
// gat_main: R3 structure (raw adj, full-j per block, direct output) with the
// whb S-fragments double-buffered across iterations (manual rotation,
// named buffers, literal indices).  grid 256 blocks x 512 thr.
// ---------------------------------------------------------------------------
__global__ void __launch_bounds__(512, 2) gat_main(
    const int* __restrict__ adj, const uint16_t* __restrict__ whb,
    const uint16_t* __restrict__ whtb, const uint16_t* __restrict__ a2b,
    const float* __restrict__ s1, const float* __restrict__ whf,
    float* __restrict__ out) {
  __shared__ float O_lds[8][16][128];                    // 64 KB (2-pass merge)
  __shared__ __align__(16) uint16_t plds[8][32][40];     // 20.5 KB, pitch 80B
  __shared__ float m_lds[8][32], l_lds[8][32];
  __shared__ float ew_lds[8][32], linv_lds[32];

  const int tid = threadIdx.x;
  const int wv = tid >> 6;
  const int lane = tid & 63;
  const int ln = lane & 15;
  const int lg = lane >> 4;
  const int ibase = blockIdx.x * 32;

  bf16x8 af[2][4];
#pragma unroll
  for (int it = 0; it < 2; ++it)
#pragma unroll
    for (int ks = 0; ks < 4; ++ks)
      af[it][ks] = *(const bf16x8*)(a2b + (size_t)(ibase + it * 16 + ln) * FDIM + ks * 32 + lg * 8);

  float s1v[2][4];
#pragma unroll
  for (int it = 0; it < 2; ++it)
#pragma unroll
    for (int r = 0; r < 4; ++r)
      s1v[it][r] = s1[ibase + it * 16 + lg * 4 + r];

  const int* adjbase = adj + (size_t)(ibase + lg * 4) * N_NODES + ln;

  float mrun[2][4], lsum[2][4];
#pragma unroll
  for (int it = 0; it < 2; ++it)
#pragma unroll
    for (int r = 0; r < 4; ++r) { mrun[it][r] = -INFINITY; lsum[it][r] = 0.f; }
  f32x4 O[2][8];
#pragma unroll
  for (int it = 0; it < 2; ++it)
#pragma unroll
    for (int ft = 0; ft < 8; ++ft) O[it][ft] = (f32x4){0.f, 0.f, 0.f, 0.f};

  const int j0 = wv * (N_NODES / 8);                     // 1024 j per wave

  bf16x8 bw0[2][4], bw1[2][4];
  GAT_LOADB(bw0, j0);

#pragma unroll 1
  for (int it2 = 0; it2 < 16; ++it2) {
    const int jbA = j0 + it2 * 64;
    const int jbB = jbA + 32;
    GAT_LOADB(bw1, jbB);           // prefetch chunk B while computing A
    GAT_BODY(bw0, jbA);
    const int jbC = (it2 < 15) ? jbA + 64 : j0;   // tail reload harmless
    GAT_LOADB(bw0, jbC);           // prefetch chunk A' while computing B
    GAT_BODY(bw1, jbB);
  }

  // reduce per-lane l partials over the 16-lane group
#pragma unroll
  for (int off = 1; off <= 8; off <<= 1)
#pragma unroll
    for (int it = 0; it < 2; ++it)
#pragma unroll
      for (int r = 0; r < 4; ++r) lsum[it][r] += __shfl_xor(lsum[it][r], off);

  if (ln == 0) {
#pragma unroll
    for (int it = 0; it < 2; ++it)
#pragma unroll
      for (int r = 0; r < 4; ++r) {
        m_lds[wv][it * 16 + lg * 4 + r] = mrun[it][r];
        l_lds[wv][it * 16 + lg * 4 + r] = lsum[it][r];
      }
  }
  __syncthreads();

  if (tid < 32) {
    float ms = -INFINITY;
#pragma unroll
    for (int w2 = 0; w2 < 8; ++w2) ms = fmaxf(ms, m_lds[w2][tid]);
    float L = 0.f;
#pragma unroll
    for (int w2 = 0; w2 < 8; ++w2) {
      float x = __expf(m_lds[w2][tid] - ms);
      ew_lds[w2][tid] = x;
      L += l_lds[w2][tid] * x;
    }
    linv_lds[tid] = 1.0f / L;
  }
  __syncthreads();

  // two-pass merge: 16 rows at a time through the 64KB buffer
#pragma unroll
  for (int h = 0; h < 2; ++h) {
#pragma unroll
    for (int ft = 0; ft < 8; ++ft)
#pragma unroll
      for (int r = 0; r < 4; ++r)
        O_lds[wv][lg * 4 + r][ft * 16 + ln] = O[h][ft][r];
    __syncthreads();
#pragma unroll
    for (int k = 0; k < 4; ++k) {
      int idx = tid + k * 512;
      int r = idx >> 7, f = idx & 127;
      float v = 0.f;
#pragma unroll
      for (int w2 = 0; w2 < 8; ++w2) v += O_lds[w2][r][f] * ew_lds[w2][h * 16 + r];
      v *= linv_lds[h * 16 + r];
      int row = ibase + h * 16 + r;
      v += BETA * whf[(size_t)row * FDIM + f];
      out[(size_t)row * FDIM + f] = (v > 0.f) ? v : (__expf(v) - 1.0f);
    }
    if (h == 0) __syncthreads();
  }
}

// ---------------------------------------------------------------------------
extern "C" void kernel_launch(void* const* d_in, const int* in_sizes, int n_in,
                              void* d_out, int out_size, void* d_ws, size_t ws_size,
                              hipStream_t stream) {
  const float* h   = (const float*)d_in[0];
  const int*   adj = (const int*)d_in[1];
  const float* w   = (const float*)d_in[3];
  const float* a   = (const float*)d_in[4];
  float* out = (float*)d_out;

  char* ws = (char*)d_ws;
  float*    whf  = (float*)ws;                     // 4 MB
  uint16_t* whb  = (uint16_t*)(ws + (4 << 20));    // 2 MB
  uint16_t* whtb = (uint16_t*)(ws + (6 << 20));    // 2 MB
  uint16_t* a2b  = (uint16_t*)(ws + (8 << 20));    // 2 MB
  float*    s1   = (float*)(ws + (10 << 20));      // 32 KB

  prep_wh<<<N_NODES / 32, 256, 0, stream>>>(h, w, whf, whb, whtb);
  prep_s1<<<N_NODES / 32, 256, 0, stream>>>(whf, a, s1, a2b);
  gat_main<<<N_NODES / 32, 512, 0, stream>>>(adj, whb, whtb, a2b, s1, whf, out);
}

// Round 11
// 190.631 us; speedup vs baseline: 1.6867x; 1.6867x over previous
//
#include <hip/hip_runtime.h>
#include <hip/hip_bf16.h>
#include <stdint.h>
#include <math.h>

#define N_NODES 8192
#define FDIM 128
#define LRELU_ALPHA 0.2f
#define BETA 0.3f
#define NEGV -9000000000000000.0f
#define THR 8.0f

typedef __attribute__((ext_vector_type(8))) short bf16x8;
typedef __attribute__((ext_vector_type(4))) float f32x4;
typedef __attribute__((ext_vector_type(4))) int i32x4;

__device__ __forceinline__ uint16_t f2b(float x) {
  union { float f; uint32_t u; } v; v.f = x;
  uint32_t r = v.u + 0x7FFFu + ((v.u >> 16) & 1u);
  return (uint16_t)(r >> 16);
}

// ---------------------------------------------------------------------------
// prep_wh: Wh = h @ w.  Writes Wh fp32, Wh bf16 (row-major), Wh^T bf16.
// ---------------------------------------------------------------------------
__global__ void __launch_bounds__(256) prep_wh(
    const float* __restrict__ h, const float* __restrict__ w,
    float* __restrict__ whf, uint16_t* __restrict__ whb,
    uint16_t* __restrict__ whtb) {
  __shared__ float hs[32][128];
  const int t = threadIdx.x;
  const int rb = blockIdx.x * 32;
#pragma unroll
  for (int k = 0; k < 16; ++k) {
    int idx = t + k * 256;
    int r = idx >> 7, c = idx & 127;
    hs[r][c] = h[(size_t)(rb + r) * FDIM + c];
  }
  __syncthreads();
  const int c = t & 127;
  const int half = t >> 7;
  const int r0 = half * 16;
  float acc[16];
#pragma unroll
  for (int k = 0; k < 16; ++k) acc[k] = 0.f;
  for (int kk = 0; kk < 128; ++kk) {
    float wv = w[kk * FDIM + c];
#pragma unroll
    for (int k = 0; k < 16; ++k) acc[k] += hs[r0 + k][kk] * wv;
  }
  uint16_t tb[16];
#pragma unroll
  for (int k = 0; k < 16; ++k) {
    int r = rb + r0 + k;
    whf[(size_t)r * FDIM + c] = acc[k];
    uint16_t b = f2b(acc[k]);
    whb[(size_t)r * FDIM + c] = b;
    tb[k] = b;
  }
  uint16_t* dst = whtb + (size_t)c * N_NODES + rb + r0;
  bf16x8 v0, v1;
#pragma unroll
  for (int k = 0; k < 8; ++k) { v0[k] = (short)tb[k]; v1[k] = (short)tb[k + 8]; }
  *(bf16x8*)(dst) = v0;
  *(bf16x8*)(dst + 8) = v1;
}

// ---------------------------------------------------------------------------
// prep_s1: s1[i] = dot(Wh[i], a1[i]);  a2 -> bf16.
// ---------------------------------------------------------------------------
__global__ void __launch_bounds__(256) prep_s1(
    const float* __restrict__ whf, const float* __restrict__ a,
    float* __restrict__ s1, uint16_t* __restrict__ a2b) {
  const int t = threadIdx.x;
  const int rb = blockIdx.x * 32;
  const int wv = t >> 6;
  const int lane = t & 63;
  const int r = rb + wv * 8 + (lane >> 3);
  const int c0 = (lane & 7) * 16;
  float s = 0.f;
#pragma unroll
  for (int k = 0; k < 16; ++k) {
    s += whf[(size_t)r * FDIM + c0 + k] * a[(size_t)r * 256 + c0 + k];
  }
  s += __shfl_xor(s, 1);
  s += __shfl_xor(s, 2);
  s += __shfl_xor(s, 4);
  if ((lane & 7) == 0) s1[r] = s;
#pragma unroll
  for (int k = 0; k < 16; ++k) {
    int idx = t + k * 256;
    int rr = idx >> 7, cc = idx & 127;
    a2b[(size_t)(rb + rr) * FDIM + cc] = f2b(a[(size_t)(rb + rr) * 256 + 128 + cc]);
  }
}

// ---------------------------------------------------------------------------
// gat_main: R3 structure with SWAPPED S-MFMA (S^T layout, i = lane&15).
// P never touches LDS: packed bf16 in-register, redistributed to the PV
// A-fragment with a static 16-shuffle exchange.  grid 256 blocks x 512 thr.
// ---------------------------------------------------------------------------
__global__ void __launch_bounds__(512, 2) gat_main(
    const int* __restrict__ adj, const uint16_t* __restrict__ whb,
    const uint16_t* __restrict__ whtb, const uint16_t* __restrict__ a2b,
    const float* __restrict__ s1, const float* __restrict__ whf,
    float* __restrict__ out) {
  __shared__ float O_lds[8][16][128];                    // 64 KB (2-pass merge)
  __shared__ float m_lds[8][32], l_lds[8][32];
  __shared__ float ew_lds[8][32], linv_lds[32];

  const int tid = threadIdx.x;
  const int wv = tid >> 6;
  const int lane = tid & 63;
  const int ln = lane & 15;
  const int lg = lane >> 4;
  const int ibase = blockIdx.x * 32;

  // a2 fragments: lane holds a2[i=ibase+it*16+ln][k-slice].  Identical bytes
  // serve as the swapped-MFMA B operand (B[k][col=i]).
  bf16x8 af[2][4];
#pragma unroll
  for (int it = 0; it < 2; ++it)
#pragma unroll
    for (int ks = 0; ks < 4; ++ks)
      af[it][ks] = *(const bf16x8*)(a2b + (size_t)(ibase + it * 16 + ln) * FDIM + ks * 32 + lg * 8);

  float s1v[2];
#pragma unroll
  for (int it = 0; it < 2; ++it) s1v[it] = s1[ibase + it * 16 + ln];

  const size_t adjr0 = (size_t)(ibase + ln) * N_NODES;
  const size_t adjr1 = (size_t)(ibase + 16 + ln) * N_NODES;

  float mrun[2] = {-INFINITY, -INFINITY};
  float lsum[2] = {0.f, 0.f};
  f32x4 O[2][8];
#pragma unroll
  for (int it = 0; it < 2; ++it)
#pragma unroll
    for (int ft = 0; ft < 8; ++ft) O[it][ft] = (f32x4){0.f, 0.f, 0.f, 0.f};

  const int j0 = wv * (N_NODES / 8);                     // 1024 j per wave
  for (int jb = j0; jb < j0 + N_NODES / 8; jb += 32) {
    // adj: row i = ibase+it*16+ln, cols jb+nt*16+lg*4 .. +4  (one dwordx4 each)
    i32x4 adjv[2][2];
    adjv[0][0] = *(const i32x4*)(adj + adjr0 + jb + lg * 4);
    adjv[0][1] = *(const i32x4*)(adj + adjr0 + jb + 16 + lg * 4);
    adjv[1][0] = *(const i32x4*)(adj + adjr1 + jb + lg * 4);
    adjv[1][1] = *(const i32x4*)(adj + adjr1 + jb + 16 + lg * 4);

    // S^T = Wh_chunk . a2^T : lane reg r = S[j=jb+nt*16+lg*4+r][i=it*16+ln]
    f32x4 sacc[2][2];
#pragma unroll
    for (int it = 0; it < 2; ++it)
#pragma unroll
      for (int nt = 0; nt < 2; ++nt) sacc[it][nt] = (f32x4){0.f, 0.f, 0.f, 0.f};
#pragma unroll
    for (int nt = 0; nt < 2; ++nt)
#pragma unroll
      for (int ks = 0; ks < 4; ++ks) {
        bf16x8 b = *(const bf16x8*)(whb + (size_t)(jb + nt * 16 + ln) * FDIM + ks * 32 + lg * 8);
        sacc[0][nt] = __builtin_amdgcn_mfma_f32_16x16x32_bf16(b, af[0][ks], sacc[0][nt], 0, 0, 0);
        sacc[1][nt] = __builtin_amdgcn_mfma_f32_16x16x32_bf16(b, af[1][ks], sacc[1][nt], 0, 0, 0);
      }

    // e = mask(lrelu(s1 + S))
    float e[2][2][4];
#pragma unroll
    for (int it = 0; it < 2; ++it)
#pragma unroll
      for (int nt = 0; nt < 2; ++nt)
#pragma unroll
        for (int r = 0; r < 4; ++r) {
          float v = s1v[it] + sacc[it][nt][r];
          v = (v > 0.f) ? v : LRELU_ALPHA * v;
          e[it][nt][r] = (adjv[it][nt][r] > 0) ? v : NEGV;
        }

    // defer-max (mrun is uniform across lg for fixed ln)
    bool upd = false;
#pragma unroll
    for (int it = 0; it < 2; ++it)
#pragma unroll
      for (int nt = 0; nt < 2; ++nt)
#pragma unroll
        for (int r = 0; r < 4; ++r) upd |= (e[it][nt][r] > mrun[it] + THR);
    if (__any(upd)) {
#pragma unroll
      for (int it = 0; it < 2; ++it) {
        float mx = e[it][0][0];
#pragma unroll
        for (int nt = 0; nt < 2; ++nt)
#pragma unroll
          for (int r = 0; r < 4; ++r) mx = fmaxf(mx, e[it][nt][r]);
        mx = fmaxf(mx, __shfl_xor(mx, 16));
        mx = fmaxf(mx, __shfl_xor(mx, 32));
        float mn = fmaxf(mrun[it], mx);
        float al = __expf(mrun[it] - mn);
        mrun[it] = mn;
        lsum[it] *= al;
        // O rows are i = lg*4+r: fetch al for those i from lanes 0..15
        float alb0 = __shfl(al, lg * 4 + 0);
        float alb1 = __shfl(al, lg * 4 + 1);
        float alb2 = __shfl(al, lg * 4 + 2);
        float alb3 = __shfl(al, lg * 4 + 3);
#pragma unroll
        for (int ft = 0; ft < 8; ++ft) {
          O[it][ft][0] *= alb0;
          O[it][ft][1] *= alb1;
          O[it][ft][2] *= alb2;
          O[it][ft][3] *= alb3;
        }
      }
    }

    // p = exp(e - m); pack to bf16 pairs (truncating) in-register
    uint32_t W[2][2][2];                   // [it][nt][half]: (r0,r1) / (r2,r3)
#pragma unroll
    for (int it = 0; it < 2; ++it)
#pragma unroll
      for (int nt = 0; nt < 2; ++nt) {
        union { float f; uint32_t u; } p0, p1, p2, p3;
        p0.f = __expf(e[it][nt][0] - mrun[it]);
        p1.f = __expf(e[it][nt][1] - mrun[it]);
        p2.f = __expf(e[it][nt][2] - mrun[it]);
        p3.f = __expf(e[it][nt][3] - mrun[it]);
        lsum[it] += (p0.f + p1.f) + (p2.f + p3.f);
        W[it][nt][0] = (p1.u & 0xFFFF0000u) | (p0.u >> 16);
        W[it][nt][1] = (p3.u & 0xFFFF0000u) | (p2.u >> 16);
      }

    // exchange: PV A-frag word w of lane (ln,lg) comes from lane
    // ln + 32*(lg&1) + 16*(w>>1), nt = lg>>1.
    const int s01 = ln + ((lg & 1) << 5);
    const int s23 = s01 + 16;
    const bool hi = (lg >= 2);
    union PW { uint32_t w[4]; bf16x8 v; } pw0, pw1;
    {
      uint32_t a0 = __shfl((int)W[0][0][0], s01), b0 = __shfl((int)W[0][1][0], s01);
      uint32_t a1 = __shfl((int)W[0][0][1], s01), b1 = __shfl((int)W[0][1][1], s01);
      uint32_t a2 = __shfl((int)W[0][0][0], s23), b2 = __shfl((int)W[0][1][0], s23);
      uint32_t a3 = __shfl((int)W[0][0][1], s23), b3 = __shfl((int)W[0][1][1], s23);
      pw0.w[0] = hi ? b0 : a0;
      pw0.w[1] = hi ? b1 : a1;
      pw0.w[2] = hi ? b2 : a2;
      pw0.w[3] = hi ? b3 : a3;
    }
    {
      uint32_t a0 = __shfl((int)W[1][0][0], s01), b0 = __shfl((int)W[1][1][0], s01);
      uint32_t a1 = __shfl((int)W[1][0][1], s01), b1 = __shfl((int)W[1][1][1], s01);
      uint32_t a2 = __shfl((int)W[1][0][0], s23), b2 = __shfl((int)W[1][1][0], s23);
      uint32_t a3 = __shfl((int)W[1][0][1], s23), b3 = __shfl((int)W[1][1][1], s23);
      pw1.w[0] = hi ? b0 : a0;
      pw1.w[1] = hi ? b1 : a1;
      pw1.w[2] = hi ? b2 : a2;
      pw1.w[3] = hi ? b3 : a3;
    }

    // PV: O[i=it*16+lg*4+r][f=ft*16+ln] += P . Wh_chunk
#pragma unroll
    for (int ft = 0; ft < 8; ++ft) {
      bf16x8 bv = *(const bf16x8*)(whtb + (size_t)(ft * 16 + ln) * N_NODES + jb + lg * 8);
      O[0][ft] = __builtin_amdgcn_mfma_f32_16x16x32_bf16(pw0.v, bv, O[0][ft], 0, 0, 0);
      O[1][ft] = __builtin_amdgcn_mfma_f32_16x16x32_bf16(pw1.v, bv, O[1][ft], 0, 0, 0);
    }
  }

  // finalize per-row l: sum partials across the 4 lg groups
#pragma unroll
  for (int it = 0; it < 2; ++it) {
    lsum[it] += __shfl_xor(lsum[it], 16);
    lsum[it] += __shfl_xor(lsum[it], 32);
  }

  if (lane < 16) {
    m_lds[wv][lane] = mrun[0];
    m_lds[wv][16 + lane] = mrun[1];
    l_lds[wv][lane] = lsum[0];
    l_lds[wv][16 + lane] = lsum[1];
  }
  __syncthreads();

  if (tid < 32) {
    float ms = -INFINITY;
#pragma unroll
    for (int w2 = 0; w2 < 8; ++w2) ms = fmaxf(ms, m_lds[w2][tid]);
    float L = 0.f;
#pragma unroll
    for (int w2 = 0; w2 < 8; ++w2) {
      float x = __expf(m_lds[w2][tid] - ms);
      ew_lds[w2][tid] = x;
      L += l_lds[w2][tid] * x;
    }
    linv_lds[tid] = 1.0f / L;
  }
  __syncthreads();

  // two-pass merge: 16 rows at a time through the 64KB buffer
#pragma unroll
  for (int h = 0; h < 2; ++h) {
#pragma unroll
    for (int ft = 0; ft < 8; ++ft)
#pragma unroll
      for (int r = 0; r < 4; ++r)
        O_lds[wv][lg * 4 + r][ft * 16 + ln] = O[h][ft][r];
    __syncthreads();
#pragma unroll
    for (int k = 0; k < 4; ++k) {
      int idx = tid + k * 512;          // 0..2047 = 16 rows x 128
      int r = idx >> 7, f = idx & 127;
      float v = 0.f;
#pragma unroll
      for (int w2 = 0; w2 < 8; ++w2) v += O_lds[w2][r][f] * ew_lds[w2][h * 16 + r];
      v *= linv_lds[h * 16 + r];
      int row = ibase + h * 16 + r;
      v += BETA * whf[(size_t)row * FDIM + f];
      out[(size_t)row * FDIM + f] = (v > 0.f) ? v : (__expf(v) - 1.0f);
    }
    if (h == 0) __syncthreads();
  }
}

// ---------------------------------------------------------------------------
extern "C" void kernel_launch(void* const* d_in, const int* in_sizes, int n_in,
                              void* d_out, int out_size, void* d_ws, size_t ws_size,
                              hipStream_t stream) {
  const float* h   = (const float*)d_in[0];
  const int*   adj = (const int*)d_in[1];
  const float* w   = (const float*)d_in[3];
  const float* a   = (const float*)d_in[4];
  float* out = (float*)d_out;

  char* ws = (char*)d_ws;
  float*    whf  = (float*)ws;                     // 4 MB
  uint16_t* whb  = (uint16_t*)(ws + (4 << 20));    // 2 MB
  uint16_t* whtb = (uint16_t*)(ws + (6 << 20));    // 2 MB
  uint16_t* a2b  = (uint16_t*)(ws + (8 << 20));    // 2 MB
  float*    s1   = (float*)(ws + (10 << 20));      // 32 KB

  prep_wh<<<N_NODES / 32, 256, 0, stream>>>(h, w, whf, whb, whtb);
  prep_s1<<<N_NODES / 32, 256, 0, stream>>>(whf, a, s1, a2b);
  gat_main<<<N_NODES / 32, 512, 0, stream>>>(adj, whb, whtb, a2b, s1, whf, out);
}